// Round 2
// baseline (1158.870 us; speedup 1.0000x reference)
//
#include <hip/hip_runtime.h>
#include <stdint.h>

typedef unsigned short u16;
typedef __attribute__((ext_vector_type(8))) short bf16x8;
typedef __attribute__((ext_vector_type(4))) float f32x4;

#define SEQ    2048
#define NB     2
#define NHEAD  16
#define DHEAD  128
#define DMODEL 2048
#define DFFN   8192
#define MROWS  4096   // NB*SEQ

__device__ __forceinline__ u16 f2bf(float x) {
  union { float f; uint32_t u; } v; v.f = x;
  return (u16)((v.u + 0x7fffu + ((v.u >> 16) & 1u)) >> 16);
}
__device__ __forceinline__ float bf2f(u16 h) {
  union { uint32_t u; float f; } v; v.u = ((uint32_t)h) << 16;
  return v.f;
}
__device__ __forceinline__ void gload16(const void* g, void* l) {
  __builtin_amdgcn_global_load_lds((const __attribute__((address_space(1))) void*)g,
                                   (__attribute__((address_space(3))) void*)l,
                                   16, 0, 0);
}
__device__ __forceinline__ float blockSum256(float v) {
  __shared__ float red[4];
  #pragma unroll
  for (int m = 1; m < 64; m <<= 1) v += __shfl_xor(v, m, 64);
  int w = threadIdx.x >> 6;
  if ((threadIdx.x & 63) == 0) red[w] = v;
  __syncthreads();
  float s = red[0] + red[1] + red[2] + red[3];
  __syncthreads();
  return s;
}

// ---------------- weight transpose fp32 (R,C) -> bf16 (C,R) ----------------
__global__ void transpose_w(const float* __restrict__ in, u16* __restrict__ out, int R, int C) {
  __shared__ float tile[32][33];
  int c0 = blockIdx.x * 32, r0 = blockIdx.y * 32;
  int tx = threadIdx.x, ty = threadIdx.y;
  #pragma unroll
  for (int i = 0; i < 4; ++i)
    tile[ty + 8*i][tx] = in[(size_t)(r0 + ty + 8*i) * C + c0 + tx];
  __syncthreads();
  #pragma unroll
  for (int i = 0; i < 4; ++i)
    out[(size_t)(c0 + ty + 8*i) * R + r0 + tx] = f2bf(tile[tx][ty + 8*i]);
}

// ---- ln_first: x(B,S,2049) -> v1 = log_map(x) fp32, t1 = scale*v1/rms bf16 ----
__global__ void ln_first(const float* __restrict__ x, const float* __restrict__ scale,
                         float* __restrict__ v1, u16* __restrict__ t1) {
  int row = blockIdx.x;
  const float* xr = x + (size_t)row * (DMODEL + 1) + 1;
  float vals[8]; float ss = 0.f;
  #pragma unroll
  for (int i = 0; i < 8; ++i) {
    int idx = threadIdx.x + 256 * i;
    vals[i] = xr[idx];
    ss += vals[i] * vals[i];
  }
  ss = blockSum256(ss);
  float n = sqrtf(ss);
  float f = (n < 1e-6f) ? (1.0f - n * n * (1.0f/6.0f)) : (asinhf(n) / n);
  float rms = sqrtf(f * f * ss * (1.0f / DMODEL) + 1e-6f);
  float ir = 1.0f / rms;
  #pragma unroll
  for (int i = 0; i < 8; ++i) {
    int idx = threadIdx.x + 256 * i;
    float v = f * vals[i];
    v1[(size_t)row * DMODEL + idx] = v;
    t1[(size_t)row * DMODEL + idx] = f2bf(scale[idx] * v * ir);
  }
}

// ---- rms_mid: t = scale*u/rms(u) (tangent-space rmsnorm; log-exp cancels) ----
__global__ void rms_mid(const float* __restrict__ u, const float* __restrict__ scale,
                        u16* __restrict__ t) {
  int row = blockIdx.x;
  const float* ur = u + (size_t)row * DMODEL;
  float vals[8]; float ss = 0.f;
  #pragma unroll
  for (int i = 0; i < 8; ++i) { int idx = threadIdx.x + 256*i; vals[i] = ur[idx]; ss += vals[i]*vals[i]; }
  ss = blockSum256(ss);
  float ir = 1.0f / sqrtf(ss * (1.0f / DMODEL) + 1e-6f);
  #pragma unroll
  for (int i = 0; i < 8; ++i) {
    int idx = threadIdx.x + 256*i;
    t[(size_t)row*DMODEL + idx] = f2bf(scale[idx]*vals[i]*ir);
  }
}

// ---- final: out = exp_map_stable(u), row length 2049 ----
__global__ void final_exp(const float* __restrict__ u, float* __restrict__ out) {
  int row = blockIdx.x;
  const float* ur = u + (size_t)row * DMODEL;
  float vals[8]; float ss = 0.f;
  #pragma unroll
  for (int i = 0; i < 8; ++i) { int idx = threadIdx.x + 256*i; vals[i] = ur[idx]; ss += vals[i]*vals[i]; }
  ss = blockSum256(ss);
  float n = sqrtf(ss);
  float f = (n < 1e-6f) ? (1.0f + n*n*(1.0f/6.0f)) : (sinhf(n)/n);
  float* orow = out + (size_t)row * (DMODEL + 1);
  if (threadIdx.x == 0) orow[0] = sqrtf(1.0f + f*f*ss);
  #pragma unroll
  for (int i = 0; i < 8; ++i) { int idx = threadIdx.x + 256*i; orow[1+idx] = f*vals[i]; }
}

// ---------------- GEMM: C(M,N) = A(M,K)bf16 @ Bt(N,K)bf16^T ----------------
// EPI 0: store bf16; EPI 1: Cf = acc + add (fp32); EPI 2: gelu(acc) -> bf16
template<int EPI>
__global__ __launch_bounds__(256, 2) void gemm_bt(
    const u16* __restrict__ A, const u16* __restrict__ Bt,
    u16* __restrict__ Cb, float* Cf, const float* add,
    int M, int N, int K)
{
  __shared__ u16 As[128 * 32];
  __shared__ u16 Bs[128 * 32];
  const int tid = threadIdx.x;
  const int w = tid >> 6, lane = tid & 63;
  const int lrow = lane & 15, kq = lane >> 4;
  const int m0 = blockIdx.y * 128, n0 = blockIdx.x * 128;
  const int wm = w >> 1, wn = w & 1;
  f32x4 acc[4][4] = {};
  for (int k0 = 0; k0 < K; k0 += 32) {
    __syncthreads();
    #pragma unroll
    for (int j = 0; j < 2; ++j) {
      int ebase = j * 2048 + w * 512;      // wave-uniform element base in tile
      int e = ebase + lane * 8;
      int row = e >> 5, col = e & 31;
      gload16(A  + (size_t)(m0 + row) * K + k0 + col, &As[ebase]);
      gload16(Bt + (size_t)(n0 + row) * K + k0 + col, &Bs[ebase]);
    }
    __syncthreads();
    bf16x8 av[4], bv[4];
    #pragma unroll
    for (int i = 0; i < 4; ++i) av[i] = *(const bf16x8*)&As[(wm*64 + i*16 + lrow)*32 + kq*8];
    #pragma unroll
    for (int j = 0; j < 4; ++j) bv[j] = *(const bf16x8*)&Bs[(wn*64 + j*16 + lrow)*32 + kq*8];
    #pragma unroll
    for (int i = 0; i < 4; ++i)
      #pragma unroll
      for (int j = 0; j < 4; ++j)
        acc[i][j] = __builtin_amdgcn_mfma_f32_16x16x32_bf16(av[i], bv[j], acc[i][j], 0, 0, 0);
  }
  #pragma unroll
  for (int i = 0; i < 4; ++i)
    #pragma unroll
    for (int j = 0; j < 4; ++j)
      #pragma unroll
      for (int r = 0; r < 4; ++r) {
        int row = m0 + wm*64 + i*16 + kq*4 + r;
        int col = n0 + wn*64 + j*16 + lrow;
        size_t idx = (size_t)row * N + col;
        float v = acc[i][j][r];
        if (EPI == 0) {
          Cb[idx] = f2bf(v);
        } else if (EPI == 1) {
          Cf[idx] = v + add[idx];
        } else {
          float g = 0.5f * v * (1.0f + erff(v * 0.70710678118654752f));
          Cb[idx] = f2bf(g);
        }
      }
}

// ---- prep: split heads + per-head exp_map. in (B*S, H*DH) bf16 ->
//      Lout[(b*H+h)*S + s][d] = sinc*v (bf16), l0 = x0 component (fp32) ----
__global__ void prep_qk(const u16* __restrict__ in, const float* __restrict__ headK,
                        u16* __restrict__ Lout, float* __restrict__ l0) {
  int gid = blockIdx.x * 4 + (threadIdx.x >> 6);
  int lane = threadIdx.x & 63;
  int b = gid >> 15;            // /(H*S)=32768
  int rem = gid & 32767;
  int h = rem >> 11;            // /S=2048
  int s = rem & 2047;
  const u16* src = in + ((size_t)(b * SEQ + s)) * DMODEL + h * DHEAD + lane * 2;
  float v0 = bf2f(src[0]), v1 = bf2f(src[1]);
  float nn = v0*v0 + v1*v1;
  #pragma unroll
  for (int m = 1; m < 64; m <<= 1) nn += __shfl_xor(nn, m, 64);
  float Kh = headK[h];
  float sk = sqrtf(-Kh);
  float a = sk * sqrtf(nn);
  float f = (a < 1e-6f) ? (1.0f + a*a*(1.0f/6.0f)) : (sinhf(a) / a);
  u16* dst = Lout + (size_t)gid * DHEAD + lane * 2;
  dst[0] = f2bf(f * v0);
  dst[1] = f2bf(f * v1);
  if (lane == 0) l0[gid] = sqrtf(-1.0f/Kh + f*f*nn);
}

// ---- vtrans: vb (B*S, H*DH) bf16 -> VT[(b*H+h)*DH + d][s] bf16 ----
__global__ void vtrans(const u16* __restrict__ vb, u16* __restrict__ VT) {
  __shared__ u16 tile[32][33];
  int bh = blockIdx.x;
  int b = bh >> 4, h = bh & 15;
  int s0 = blockIdx.y * 32, d0 = blockIdx.z * 32;
  int tx = threadIdx.x, ty = threadIdx.y;
  #pragma unroll
  for (int i = 0; i < 4; ++i)
    tile[ty + 8*i][tx] = vb[((size_t)(b*SEQ + s0 + ty + 8*i)) * DMODEL + h*DHEAD + d0 + tx];
  __syncthreads();
  #pragma unroll
  for (int i = 0; i < 4; ++i)
    VT[((size_t)bh*DHEAD + d0 + ty + 8*i) * SEQ + s0 + tx] = tile[tx][ty + 8*i];
}

// ---------------- flash attention, 64 q-rows per block, 4 waves ----------------
__global__ void attn_kernel(const u16* __restrict__ Ql, const u16* __restrict__ Kl,
                            const u16* __restrict__ VT, const float* __restrict__ ql0,
                            const float* __restrict__ kl0, const float* __restrict__ headK,
                            u16* __restrict__ out) {
  __shared__ u16 klds[32 * 136];     // K tile [kpos][d], padded 128->136
  __shared__ u16 vtlds[128 * 40];    // V^T tile [d][kpos], padded 32->40
  __shared__ u16 plds[4][16 * 40];   // per-wave P transpose buffer
  __shared__ float kl0s[32];
  const int tid = threadIdx.x, w = tid >> 6, lane = tid & 63;
  const int lrow = lane & 15, kq = lane >> 4;
  const int q0 = (int)(gridDim.x - 1 - blockIdx.x) * 64;  // long blocks first
  const int bh = blockIdx.y;
  const int b = bh >> 4, h = bh & 15;
  const float Kh = headK[h];
  const float koff = -2.0f / Kh;
  const float isd = 0.088388347648318447f;   // 1/sqrt(128)
  const float NEGINF = -__builtin_inff();

  bf16x8 aq[4];
  const size_t qrow0 = (size_t)bh * SEQ + q0 + w * 16;
  #pragma unroll
  for (int dc = 0; dc < 4; ++dc)
    aq[dc] = *(const bf16x8*)&Ql[(qrow0 + lrow) * DHEAD + dc * 32 + kq * 8];
  float q0r[4];
  #pragma unroll
  for (int r = 0; r < 4; ++r) q0r[r] = ql0[qrow0 + kq * 4 + r];

  float mrow[4] = {NEGINF, NEGINF, NEGINF, NEGINF};
  float lacc[4] = {0.f, 0.f, 0.f, 0.f};
  f32x4 o[8] = {};
  const int kend = q0 + 64;
  for (int k0 = 0; k0 < kend; k0 += 32) {
    __syncthreads();
    #pragma unroll
    for (int it = 0; it < 2; ++it) {
      int flat = it * 256 + tid;
      int krow = flat >> 4, kc = flat & 15;
      *(uint4*)&klds[krow * 136 + kc * 8] =
          *(const uint4*)&Kl[((size_t)bh * SEQ + k0 + krow) * DHEAD + kc * 8];
      int vrow = flat >> 2, vc = flat & 3;
      *(uint4*)&vtlds[vrow * 40 + vc * 8] =
          *(const uint4*)&VT[((size_t)bh * DHEAD + vrow) * SEQ + k0 + vc * 8];
    }
    if (tid < 32) kl0s[tid] = kl0[(size_t)bh * SEQ + k0 + tid];
    __syncthreads();

    f32x4 sc0 = {}, sc1 = {};
    #pragma unroll
    for (int dc = 0; dc < 4; ++dc) {
      bf16x8 bk0 = *(const bf16x8*)&klds[(lrow) * 136 + dc * 32 + kq * 8];
      bf16x8 bk1 = *(const bf16x8*)&klds[(16 + lrow) * 136 + dc * 32 + kq * 8];
      sc0 = __builtin_amdgcn_mfma_f32_16x16x32_bf16(aq[dc], bk0, sc0, 0, 0, 0);
      sc1 = __builtin_amdgcn_mfma_f32_16x16x32_bf16(aq[dc], bk1, sc1, 0, 0, 0);
    }
    float p0[4], p1[4], alpha[4];
    float k00 = kl0s[lrow], k01 = kl0s[16 + lrow];
    int kg0 = k0 + lrow, kg1 = k0 + 16 + lrow;
    #pragma unroll
    for (int r = 0; r < 4; ++r) {
      int qg = q0 + w * 16 + kq * 4 + r;
      float v0 = (2.0f * (sc0[r] - q0r[r] * k00) + koff) * isd;
      float v1 = (2.0f * (sc1[r] - q0r[r] * k01) + koff) * isd;
      v0 = (kg0 <= qg) ? v0 : NEGINF;
      v1 = (kg1 <= qg) ? v1 : NEGINF;
      float best = fmaxf(v0, v1);
      #pragma unroll
      for (int mm = 1; mm < 16; mm <<= 1) best = fmaxf(best, __shfl_xor(best, mm, 16));
      float mn = fmaxf(mrow[r], best);
      alpha[r] = __expf(mrow[r] - mn);
      mrow[r] = mn;
      float e0 = __expf(v0 - mn), e1 = __expf(v1 - mn);
      p0[r] = e0; p1[r] = e1;
      float s = e0 + e1;
      #pragma unroll
      for (int mm = 1; mm < 16; mm <<= 1) s += __shfl_xor(s, mm, 16);
      lacc[r] = alpha[r] * lacc[r] + s;
    }
    #pragma unroll
    for (int r = 0; r < 4; ++r) {
      plds[w][(kq * 4 + r) * 40 + lrow]      = f2bf(p0[r]);
      plds[w][(kq * 4 + r) * 40 + 16 + lrow] = f2bf(p1[r]);
    }
    __syncthreads();
    #pragma unroll
    for (int n = 0; n < 8; ++n)
      #pragma unroll
      for (int r = 0; r < 4; ++r) o[n][r] *= alpha[r];
    bf16x8 ap = *(const bf16x8*)&plds[w][lrow * 40 + kq * 8];
    #pragma unroll
    for (int n = 0; n < 8; ++n) {
      bf16x8 bvv = *(const bf16x8*)&vtlds[(n * 16 + lrow) * 40 + kq * 8];
      o[n] = __builtin_amdgcn_mfma_f32_16x16x32_bf16(ap, bvv, o[n], 0, 0, 0);
    }
  }
  float rcl[4];
  #pragma unroll
  for (int r = 0; r < 4; ++r) rcl[r] = 1.0f / lacc[r];
  #pragma unroll
  for (int n = 0; n < 8; ++n)
    #pragma unroll
    for (int r = 0; r < 4; ++r) {
      int qg = q0 + w * 16 + kq * 4 + r;
      out[((size_t)b * SEQ + qg) * DMODEL + h * DHEAD + n * 16 + lrow] = f2bf(o[n][r] * rcl[r]);
    }
}

extern "C" void kernel_launch(void* const* d_in, const int* in_sizes, int n_in,
                              void* d_out, int out_size, void* d_ws, size_t ws_size,
                              hipStream_t stream) {
  const float* x      = (const float*)d_in[0];
  // d_in[1] = mask (causal tril; applied analytically)
  const float* scale1 = (const float*)d_in[2];
  const float* scale2 = (const float*)d_in[3];
  const float* Wq     = (const float*)d_in[4];
  const float* Wk     = (const float*)d_in[5];
  const float* Wv     = (const float*)d_in[6];
  const float* Wo     = (const float*)d_in[7];
  const float* headK  = (const float*)d_in[8];
  const float* W1     = (const float*)d_in[9];
  const float* W2     = (const float*)d_in[10];
  float* out = (float*)d_out;

  char* p = (char*)d_ws;
  size_t off = 0;
  auto take = [&](size_t bytes) -> char* {
    char* r = p + off;
    off += (bytes + 255) & ~(size_t)255;
    return r;
  };
  u16* WqT = (u16*)take((size_t)DMODEL*DMODEL*2);
  u16* WkT = (u16*)take((size_t)DMODEL*DMODEL*2);
  u16* WvT = (u16*)take((size_t)DMODEL*DMODEL*2);
  u16* WoT = (u16*)take((size_t)DMODEL*DMODEL*2);
  u16* W1T = (u16*)take((size_t)DMODEL*DFFN*2);
  u16* W2T = (u16*)take((size_t)DMODEL*DFFN*2);
  float* vres = (float*)take((size_t)MROWS*DMODEL*4);   // v1 -> u2 -> u3 (in place)
  u16* tbuf = (u16*)take((size_t)MROWS*DMODEL*2);       // t1 then t2
  u16* qb   = (u16*)take((size_t)MROWS*DMODEL*2);       // q proj, then attn_out
  u16* kb   = (u16*)take((size_t)MROWS*DMODEL*2);       // k proj (hbuf part 1)
  u16* vb   = (u16*)take((size_t)MROWS*DMODEL*2);       // v proj (hbuf part 2)
  u16* Qlb  = (u16*)take((size_t)MROWS*DMODEL*2);       // q lorentz (hbuf part 3)
  u16* Klb  = (u16*)take((size_t)MROWS*DMODEL*2);       // k lorentz (hbuf part 4)
  u16* VTb  = (u16*)take((size_t)MROWS*DMODEL*2);
  float* q0b = (float*)take((size_t)NB*NHEAD*SEQ*4);
  float* k0b = (float*)take((size_t)NB*NHEAD*SEQ*4);
  u16* hbuf = kb;       // reuse kb..Klb contiguous 64MB = MROWS*DFFN bf16
  u16* attnout = qb;    // reuse q proj buffer

  dim3 tb(32, 8);
  transpose_w<<<dim3(DMODEL/32, DMODEL/32), tb, 0, stream>>>(Wq, WqT, DMODEL, DMODEL);
  transpose_w<<<dim3(DMODEL/32, DMODEL/32), tb, 0, stream>>>(Wk, WkT, DMODEL, DMODEL);
  transpose_w<<<dim3(DMODEL/32, DMODEL/32), tb, 0, stream>>>(Wv, WvT, DMODEL, DMODEL);
  transpose_w<<<dim3(DMODEL/32, DMODEL/32), tb, 0, stream>>>(Wo, WoT, DMODEL, DMODEL);
  transpose_w<<<dim3(DFFN/32,   DMODEL/32), tb, 0, stream>>>(W1, W1T, DMODEL, DFFN);
  transpose_w<<<dim3(DMODEL/32, DFFN/32),   tb, 0, stream>>>(W2, W2T, DFFN, DMODEL);

  ln_first<<<MROWS, 256, 0, stream>>>(x, scale1, vres, tbuf);

  gemm_bt<0><<<dim3(DMODEL/128, MROWS/128), 256, 0, stream>>>(tbuf, WqT, qb, nullptr, nullptr, MROWS, DMODEL, DMODEL);
  gemm_bt<0><<<dim3(DMODEL/128, MROWS/128), 256, 0, stream>>>(tbuf, WkT, kb, nullptr, nullptr, MROWS, DMODEL, DMODEL);
  gemm_bt<0><<<dim3(DMODEL/128, MROWS/128), 256, 0, stream>>>(tbuf, WvT, vb, nullptr, nullptr, MROWS, DMODEL, DMODEL);

  prep_qk<<<NB*NHEAD*SEQ/4, 256, 0, stream>>>(qb, headK, Qlb, q0b);
  prep_qk<<<NB*NHEAD*SEQ/4, 256, 0, stream>>>(kb, headK, Klb, k0b);
  vtrans<<<dim3(NB*NHEAD, SEQ/32, DHEAD/32), tb, 0, stream>>>(vb, VTb);

  attn_kernel<<<dim3(SEQ/64, NB*NHEAD), 256, 0, stream>>>(Qlb, Klb, VTb, q0b, k0b, headK, attnout);

  gemm_bt<1><<<dim3(DMODEL/128, MROWS/128), 256, 0, stream>>>(attnout, WoT, nullptr, vres, vres, MROWS, DMODEL, DMODEL);

  rms_mid<<<MROWS, 256, 0, stream>>>(vres, scale2, tbuf);

  gemm_bt<2><<<dim3(DFFN/128, MROWS/128), 256, 0, stream>>>(tbuf, W1T, hbuf, nullptr, nullptr, MROWS, DFFN, DMODEL);

  gemm_bt<1><<<dim3(DMODEL/128, MROWS/128), 256, 0, stream>>>(hbuf, W2T, nullptr, vres, vres, MROWS, DMODEL, DFFN);

  final_exp<<<MROWS, 256, 0, stream>>>(vres, out);

  (void)in_sizes; (void)n_in; (void)out_size; (void)ws_size;
}